// Round 24
// baseline (41.452 us; speedup 1.0000x reference)
//
#include <hip/hip_runtime.h>
#include <hip/hip_bf16.h>

#define DM 1024
#define SD 32
#define NG 8
#define GD 128
#define BS 4
#define TT 4096
#define CL 64        // chunk length
#define NC (TT/CL)   // 64 chunks

typedef __attribute__((ext_vector_type(8))) short short8;
typedef __attribute__((ext_vector_type(4))) short short4v;
typedef __attribute__((ext_vector_type(4))) float f32x4;

// workspace layout (bytes), 16B aligned
#define WS_PAL   0                         // f32[8][64][32] = 64KB (powAL[g][j][n] = (a^64)^j)
#define WS_BU    65536                     // bf16[4][64][8][32][64] = 8MB  Bu in [n][t] layout
#define WS_CARRY (WS_BU + 8388608)         // f32[4][8][64][32] = 256KB, layout [b][g][c][n]

__device__ __forceinline__ unsigned short f2bf(float f) {
  __hip_bfloat16 h = __float2bfloat16(f);
  return __builtin_bit_cast(unsigned short, h);
}
__device__ __forceinline__ float bf2f(unsigned short h) {
  return __uint_as_float(((unsigned)h) << 16);
}
__device__ __forceinline__ float softplus_f(float x) {
  return (x > 20.f) ? x : log1pf(expf(x));
}
__device__ __forceinline__ short8 pack8(float4 a, float4 b) {
  short8 h;
  h[0]=(short)f2bf(a.x); h[1]=(short)f2bf(a.y); h[2]=(short)f2bf(a.z); h[3]=(short)f2bf(a.w);
  h[4]=(short)f2bf(b.x); h[5]=(short)f2bf(b.y); h[6]=(short)f2bf(b.z); h[7]=(short)f2bf(b.w);
  return h;
}

// ---------------- KA: Bu GEMM + parallel carry reduce + Bu store (NO scan, NO LDS) ----------------
__global__ __launch_bounds__(64) void ka_bu(const float* __restrict__ u,
                                            const float* __restrict__ A_log,
                                            const float* __restrict__ B_param,
                                            const float* __restrict__ dt_logit,
                                            unsigned char* __restrict__ ws) {
  const int bx = blockIdx.x;
  const int g = bx & (NG - 1);               // g-fastest dispatch (R19 win)
  const int c = (bx >> 3) & (NC - 1);
  const int b = bx >> 9;
  const int l = threadIdx.x;
  const int lr = l & 15, lh = l >> 4;

  const float dtg = 0.001f + 0.099f * (1.f / (1.f + expf(-dt_logit[g])));

  // per-column decay/frac (n' = nt*16 + lr)
  float fracv[2], l2v[2];
  #pragma unroll
  for (int nt = 0; nt < 2; ++nt) {
    int np = nt * 16 + lr;
    float A = -softplus_f(A_log[g * SD + np]);
    float a = expf(A * dtg);
    fracv[nt] = (fabsf(A) > 1e-6f) ? (a - 1.f) / A : dtg;
    l2v[nt] = A * dtg * 1.44269504f;
  }

  const float* bp = B_param + (size_t)g * SD * GD;
  short8 bfr[4][2];
  #pragma unroll
  for (int kt = 0; kt < 4; ++kt)
    #pragma unroll
    for (int nt = 0; nt < 2; ++nt) {
      const float* p = bp + (size_t)(nt * 16 + lr) * GD + kt * 32 + lh * 8;
      float4 v0 = *(const float4*)p;
      float4 v1 = *(const float4*)(p + 4);
      float s = fracv[nt];
      v0.x*=s; v0.y*=s; v0.z*=s; v0.w*=s;
      v1.x*=s; v1.y*=s; v1.z*=s; v1.w*=s;
      bfr[kt][nt] = pack8(v0, v1);
    }

  // u fragments: 2-deep kt pipeline (R19-proven)
  const float* up = u + ((size_t)b * TT + (size_t)c * CL) * DM + g * GD;
  float4 ub[2][4][2];
  #pragma unroll
  for (int kt = 0; kt < 2; ++kt)
    #pragma unroll
    for (int m = 0; m < 4; ++m) {
      const float* p = up + (size_t)(m * 16 + lr) * DM + kt * 32 + lh * 8;
      ub[kt][m][0] = *(const float4*)p;
      ub[kt][m][1] = *(const float4*)(p + 4);
    }

  f32x4 acc[4][2];
  #pragma unroll
  for (int m = 0; m < 4; ++m)
    #pragma unroll
    for (int nt = 0; nt < 2; ++nt)
      #pragma unroll
      for (int j = 0; j < 4; ++j) acc[m][nt][j] = 0.f;

  #pragma unroll
  for (int kt = 0; kt < 4; ++kt) {
    short8 af[4];
    #pragma unroll
    for (int m = 0; m < 4; ++m)
      af[m] = pack8(ub[kt & 1][m][0], ub[kt & 1][m][1]);
    if (kt < 2) {
      #pragma unroll
      for (int m = 0; m < 4; ++m) {
        const float* p = up + (size_t)(m * 16 + lr) * DM + (kt + 2) * 32 + lh * 8;
        ub[kt & 1][m][0] = *(const float4*)p;
        ub[kt & 1][m][1] = *(const float4*)(p + 4);
      }
    }
    #pragma unroll
    for (int m = 0; m < 4; ++m)
      #pragma unroll
      for (int nt = 0; nt < 2; ++nt)
        acc[m][nt] = __builtin_amdgcn_mfma_f32_16x16x32_bf16(af[m], bfr[kt][nt], acc[m][nt], 0, 0, 0);
  }

  // ---- carry via parallel weighted reduce (R10 K1, proven): carry[n] = sum_t a^(63-t)*Bu[t][n] ----
  float part[2];
  #pragma unroll
  for (int nt = 0; nt < 2; ++nt) {
    float r1 = exp2f(-l2v[nt]);         // a^{-1}
    float pnt = 0.f;
    #pragma unroll
    for (int m = 0; m < 4; ++m) {
      float wm = exp2f(l2v[nt] * (float)(63 - 16 * m - 4 * lh));   // a^(63-t) at j=0
      #pragma unroll
      for (int j = 0; j < 4; ++j) {
        pnt = fmaf(wm, acc[m][nt][j], pnt);
        wm *= r1;
      }
    }
    part[nt] = pnt;
  }
  #pragma unroll
  for (int nt = 0; nt < 2; ++nt) {
    part[nt] += __shfl_xor(part[nt], 16);
    part[nt] += __shfl_xor(part[nt], 32);
  }
  float* carry = (float*)(ws + WS_CARRY);
  if (l < 32)
    carry[((size_t)(b * NG + g) * NC + c) * SD + l] = part[(l >> 4) & 1];

  // ---- Bu -> global bf16 in [n][t] layout (8x 8B stores; no LDS, no barrier) ----
  unsigned short* bu = (unsigned short*)(ws + WS_BU) + ((size_t)((b * NC + c) * NG + g)) * CL * SD;
  #pragma unroll
  for (int m = 0; m < 4; ++m)
    #pragma unroll
    for (int nt = 0; nt < 2; ++nt) {
      short4v h4;
      h4[0] = (short)f2bf(acc[m][nt][0]);
      h4[1] = (short)f2bf(acc[m][nt][1]);
      h4[2] = (short)f2bf(acc[m][nt][2]);
      h4[3] = (short)f2bf(acc[m][nt][3]);
      *(short4v*)(bu + (nt * 16 + lr) * CL + m * 16 + lh * 4) = h4;
    }

  // 8 special blocks emit powAL for KB
  if (b == 0 && c == 0 && l < SD) {
    float A = -softplus_f(A_log[g * SD + l]);
    float a = expf(A * dtg);
    float aL = 1.f;
    #pragma unroll
    for (int t = 0; t < CL; ++t) aL *= a;   // a^64
    float* powAL = (float*)(ws + WS_PAL);
    float q = 1.f;
    #pragma unroll
    for (int j = 0; j < CL; ++j) {
      powAL[(g * CL + j) * SD + l] = q;     // aL^j
      q *= aL;
    }
  }
}

// ---------------- KB: prefix + in-register scan-with-carry-in + C GEMM + coalesced y store ----------------
__global__ __launch_bounds__(128) void kb_y(const float* __restrict__ u,
                                            const float* __restrict__ state0,
                                            const float* __restrict__ A_log,
                                            const float* __restrict__ C,
                                            const float* __restrict__ Dp,
                                            const float* __restrict__ dt_logit,
                                            unsigned char* __restrict__ ws,
                                            float* __restrict__ y,
                                            float* __restrict__ sfin) {
  const int bx = blockIdx.x;
  const int g = bx & (NG - 1);               // g-fastest dispatch
  const int c = (bx >> 3) & (NC - 1);
  const int b = bx >> 9;
  const int tid = threadIdx.x;
  const int w = tid >> 6;          // wave 0..1 -> d-half
  const int l = tid & 63;
  const int lr = l & 15, lh = l >> 4;
  const int n = l & 31;

  const float* powAL = (const float*)(ws + WS_PAL) + g * CL * SD;
  const float* carry = (const float*)(ws + WS_CARRY) + (size_t)(b * NG + g) * NC * SD;  // [c][n]
  const unsigned short* bu = (const unsigned short*)(ws + WS_BU) + ((size_t)((b * NC + c) * NG + g)) * CL * SD;

  __shared__ __align__(16) unsigned short sSt[CL * SD];   // 4KB scanned states (bf16)
  __shared__ __align__(16) float sY[32 * 132];            // 16896B transpose buffer

  // ---- issue Bu row loads EARLY (in flight during prefix); lane tid<32 owns chain n=tid ----
  short8 bu8[8];
  if (tid < 32) {
    #pragma unroll
    for (int q = 0; q < 8; ++q)
      bu8[q] = *(const short8*)(bu + tid * CL + q * 8);
  }

  bool need_u;
  {
    float2 dpc = *(const float2*)(Dp + g * GD + l * 2);
    need_u = __ballot((dpc.x != 0.f) || (dpc.y != 0.f)) != 0ULL;
  }

  const float dtg = 0.001f + 0.099f * (1.f / (1.f + expf(-dt_logit[g])));
  const float a_n = expf(-softplus_f(A_log[g * SD + n]) * dtg);

  // --- chunk-entry prefix (per wave, redundant): weighted sum over carries ---
  float p;
  {
    float a0 = 0.f, a1 = 0.f, a2 = 0.f, a3 = 0.f;
    int cc = 0;
    while (cc + 8 <= c) {
      float ca[8], wt[8];
      #pragma unroll
      for (int e = 0; e < 8; ++e) {
        ca[e] = carry[(cc + e) * SD + n];
        wt[e] = powAL[(c - 1 - cc - e) * SD + n];
      }
      a0 = fmaf(wt[0], ca[0], a0); a1 = fmaf(wt[1], ca[1], a1);
      a2 = fmaf(wt[2], ca[2], a2); a3 = fmaf(wt[3], ca[3], a3);
      a0 = fmaf(wt[4], ca[4], a0); a1 = fmaf(wt[5], ca[5], a1);
      a2 = fmaf(wt[6], ca[6], a2); a3 = fmaf(wt[7], ca[7], a3);
      cc += 8;
    }
    for (; cc < c; ++cc)
      a0 = fmaf(powAL[(c - 1 - cc) * SD + n], carry[cc * SD + n], a0);
    p = fmaf(state0[(b * NG + g) * SD + n], powAL[c * SD + n], (a0 + a1) + (a2 + a3));
  }
  if (w == 0 && c == NC - 1 && l < SD) {
    const float aL = powAL[SD + l];   // aL^1
    sfin[(b * NG + g) * SD + l] = fmaf(p, aL, carry[(NC - 1) * SD + l]);
  }

  // ---- scan with carry-in: s_true[t] directly (replaces powA correction) ----
  if (tid < 32) {
    float s = p;                      // chunk-entry state for chain n=tid
    #pragma unroll
    for (int q = 0; q < 8; ++q)
      #pragma unroll
      for (int e = 0; e < 8; ++e) {
        int t = q * 8 + e;
        s = fmaf(s, a_n, bf2f((unsigned short)bu8[q][e]));
        sSt[t * SD + tid] = f2bf(s);
      }
  }
  __syncthreads();

  // --- state fragments straight from LDS (B operand, col=t, k=n) ---
  short8 sf[4];
  #pragma unroll
  for (int tt = 0; tt < 4; ++tt)
    sf[tt] = *(const short8*)(sSt + (tt * 16 + lr) * SD + lh * 8);

  // --- GEMM (swapped): D[d][t] = sum_n C[d][n]*s[t][n]; wave w owns d-half w ---
  const float* cp = C + (size_t)g * GD * SD;
  const size_t rowbase = ((size_t)b * TT + (size_t)c * CL) * DM + g * GD;

  short8 cf[4];
  #pragma unroll
  for (int dd = 0; dd < 4; ++dd) {
    int d = (w * 4 + dd) * 16 + lr;
    const float* pp = cp + (size_t)d * SD + lh * 8;
    float4 v0 = *(const float4*)pp;
    float4 v1 = *(const float4*)(pp + 4);
    cf[dd] = pack8(v0, v1);
  }
  f32x4 acc[4][4];
  #pragma unroll
  for (int dd = 0; dd < 4; ++dd)
    #pragma unroll
    for (int tt = 0; tt < 4; ++tt) {
      f32x4 z;
      #pragma unroll
      for (int j = 0; j < 4; ++j) z[j] = 0.f;
      acc[dd][tt] = __builtin_amdgcn_mfma_f32_16x16x32_bf16(cf[dd], sf[tt], z, 0, 0, 0);
    }

  // --- epilogue: LDS transpose (two 32-t halves) -> fully coalesced y stores ---
  const int sd4 = (tid & 31) * 4;
  float4 dpv = *(const float4*)(Dp + g * GD + sd4);

  #pragma unroll
  for (int tp = 0; tp < 2; ++tp) {
    if (tp) __syncthreads();
    #pragma unroll
    for (int dd = 0; dd < 4; ++dd)
      #pragma unroll
      for (int q = 0; q < 2; ++q) {
        int tt = tp * 2 + q;
        int tl = q * 16 + lr;
        int d0 = (w * 4 + dd) * 16 + lh * 4;
        *(float4*)(sY + tl * 132 + d0) = (float4){acc[dd][tt][0], acc[dd][tt][1],
                                                  acc[dd][tt][2], acc[dd][tt][3]};
      }
    __syncthreads();
    #pragma unroll
    for (int r = 0; r < 8; ++r) {
      int tl = r * 4 + (tid >> 5);
      int t = tp * 32 + tl;
      float4 v = *(const float4*)(sY + tl * 132 + sd4);
      size_t off = rowbase + (size_t)t * DM + sd4;
      if (need_u) {
        float4 u4 = *(const float4*)(u + off);
        v.x += dpv.x * u4.x; v.y += dpv.y * u4.y;
        v.z += dpv.z * u4.z; v.w += dpv.w * u4.w;
      }
      *(float4*)(y + off) = v;
    }
  }
}

extern "C" void kernel_launch(void* const* d_in, const int* in_sizes, int n_in,
                              void* d_out, int out_size, void* d_ws, size_t ws_size,
                              hipStream_t stream) {
  const float* u       = (const float*)d_in[0];
  const float* state0  = (const float*)d_in[1];
  const float* A_log   = (const float*)d_in[2];
  const float* B_param = (const float*)d_in[3];
  const float* C       = (const float*)d_in[4];
  const float* Dp      = (const float*)d_in[5];
  const float* dtl     = (const float*)d_in[6];
  float* y = (float*)d_out;
  unsigned char* ws = (unsigned char*)d_ws;
  float* sfin = y + (size_t)BS * TT * DM;

  ka_bu<<<dim3(BS * NG * NC), dim3(64), 0, stream>>>(u, A_log, B_param, dtl, ws);
  kb_y<<<dim3(BS * NG * NC), dim3(128), 0, stream>>>(u, state0, A_log, C, Dp, dtl, ws, y, sfin);
}

// Round 25
// 40.746 us; speedup vs baseline: 1.0173x; 1.0173x over previous
//
#include <hip/hip_runtime.h>
#include <hip/hip_bf16.h>

#define DM 1024
#define SD 32
#define NG 8
#define GD 128
#define BS 4
#define TT 4096
#define CL 64        // chunk length
#define NC (TT/CL)   // 64 chunks

typedef __attribute__((ext_vector_type(8))) short short8;
typedef __attribute__((ext_vector_type(4))) float f32x4;

// workspace layout (bytes), 16B aligned
#define WS_POWA  0                         // f32[8][64][32]  = 64KB  (powA[g][t][n] = Abar^(t+1))
#define WS_STL   65536                     // bf16[4][64][8][64][32] = 8MB (local-scan states)
#define WS_CARRY (WS_STL + 8388608)        // f32[4][8][64][32] = 256KB, layout [b][g][c][n]
#define WS_PAL   (WS_CARRY + 262144)       // f32[8][64][32] = 64KB (powAL[g][j][n] = (a^64)^j)

__device__ __forceinline__ unsigned short f2bf(float f) {
  __hip_bfloat16 h = __float2bfloat16(f);
  return __builtin_bit_cast(unsigned short, h);
}
__device__ __forceinline__ float bf2f(unsigned short h) {
  return __uint_as_float(((unsigned)h) << 16);
}
__device__ __forceinline__ float softplus_f(float x) {
  return (x > 20.f) ? x : log1pf(expf(x));
}
__device__ __forceinline__ short8 pack8(float4 a, float4 b) {
  short8 h;
  h[0]=(short)f2bf(a.x); h[1]=(short)f2bf(a.y); h[2]=(short)f2bf(a.z); h[3]=(short)f2bf(a.w);
  h[4]=(short)f2bf(b.x); h[5]=(short)f2bf(b.y); h[6]=(short)f2bf(b.z); h[7]=(short)f2bf(b.w);
  return h;
}

// ---------------- KA: 2 chunks/block, cross-chunk pipelined Bu GEMM + local scans ----------------
__global__ __launch_bounds__(64) void ka_bu_scan(const float* __restrict__ u,
                                                 const float* __restrict__ A_log,
                                                 const float* __restrict__ B_param,
                                                 const float* __restrict__ dt_logit,
                                                 unsigned char* __restrict__ ws) {
  const int bx = blockIdx.x;
  const int g = bx & (NG - 1);               // g-fastest dispatch (R19 win)
  const int pc = (bx >> 3) & (NC / 2 - 1);   // chunk pair 0..31
  const int b = bx >> 8;
  const int c0 = pc * 2;
  const int l = threadIdx.x;
  const int lr = l & 15, lh = l >> 4;

  const float dtg = 0.001f + 0.099f * (1.f / (1.f + expf(-dt_logit[g])));

  float fracv[2];
  #pragma unroll
  for (int nt = 0; nt < 2; ++nt) {
    int n = nt * 16 + lr;
    float A = -softplus_f(A_log[g * SD + n]);
    float a = expf(A * dtg);
    fracv[nt] = (fabsf(A) > 1e-6f) ? (a - 1.f) / A : dtg;
  }
  float a_scan;
  {
    float A = -softplus_f(A_log[g * SD + (l & 31)]);
    a_scan = expf(A * dtg);
  }

  // B fragments ONCE (shared by both chunks)
  const float* bp = B_param + (size_t)g * SD * GD;
  short8 bfr[4][2];
  #pragma unroll
  for (int kt = 0; kt < 4; ++kt)
    #pragma unroll
    for (int nt = 0; nt < 2; ++nt) {
      const float* p = bp + (size_t)(nt * 16 + lr) * GD + kt * 32 + lh * 8;
      float4 v0 = *(const float4*)p;
      float4 v1 = *(const float4*)(p + 4);
      float s = fracv[nt];
      v0.x*=s; v0.y*=s; v0.z*=s; v0.w*=s;
      v1.x*=s; v1.y*=s; v1.z*=s; v1.w*=s;
      bfr[kt][nt] = pack8(v0, v1);
    }

  __shared__ __align__(16) float sBu[CL * 33];            // 8448B
  __shared__ __align__(16) unsigned short sSt[CL * SD];   // 4096B
  float* carry = (float*)(ws + WS_CARRY);

  const float* upb = u + ((size_t)b * TT + (size_t)c0 * CL) * DM + g * GD;

  // prologue: chunk0 kt0,1 loads
  float4 ub[2][4][2];
  #pragma unroll
  for (int kt = 0; kt < 2; ++kt)
    #pragma unroll
    for (int m = 0; m < 4; ++m) {
      const float* p = upb + (size_t)(m * 16 + lr) * DM + kt * 32 + lh * 8;
      ub[kt][m][0] = *(const float4*)p;
      ub[kt][m][1] = *(const float4*)(p + 4);
    }

  #pragma unroll
  for (int ch = 0; ch < 2; ++ch) {
    const float* up  = upb + (size_t)ch * CL * DM;
    const float* upn = upb + (size_t)(ch + 1) * CL * DM;   // next chunk (used only ch==0)

    f32x4 acc[4][2];
    #pragma unroll
    for (int m = 0; m < 4; ++m)
      #pragma unroll
      for (int nt = 0; nt < 2; ++nt)
        #pragma unroll
        for (int j = 0; j < 4; ++j) acc[m][nt][j] = 0.f;

    #pragma unroll
    for (int kt = 0; kt < 4; ++kt) {
      short8 af[4];
      #pragma unroll
      for (int m = 0; m < 4; ++m)
        af[m] = pack8(ub[kt & 1][m][0], ub[kt & 1][m][1]);
      if (kt < 2) {        // refill with this chunk's kt+2
        #pragma unroll
        for (int m = 0; m < 4; ++m) {
          const float* p = up + (size_t)(m * 16 + lr) * DM + (kt + 2) * 32 + lh * 8;
          ub[kt & 1][m][0] = *(const float4*)p;
          ub[kt & 1][m][1] = *(const float4*)(p + 4);
        }
      } else if (ch == 0) { // cross-chunk prefetch: chunk1 kt-2 -> in flight through scan/store
        #pragma unroll
        for (int m = 0; m < 4; ++m) {
          const float* p = upn + (size_t)(m * 16 + lr) * DM + (kt - 2) * 32 + lh * 8;
          ub[kt & 1][m][0] = *(const float4*)p;
          ub[kt & 1][m][1] = *(const float4*)(p + 4);
        }
      }
      #pragma unroll
      for (int m = 0; m < 4; ++m)
        #pragma unroll
        for (int nt = 0; nt < 2; ++nt)
          acc[m][nt] = __builtin_amdgcn_mfma_f32_16x16x32_bf16(af[m], bfr[kt][nt], acc[m][nt], 0, 0, 0);
    }

    #pragma unroll
    for (int m = 0; m < 4; ++m)
      #pragma unroll
      for (int nt = 0; nt < 2; ++nt)
        #pragma unroll
        for (int j = 0; j < 4; ++j) {
          int t = m * 16 + lh * 4 + j;   // C/D: row=(lane>>4)*4+j, col=lane&15
          sBu[t * 33 + (nt * 16 + lr)] = acc[m][nt][j];
        }
    __syncthreads();

    if (l < SD) {
      float s = 0.f;
      #pragma unroll
      for (int t = 0; t < CL; ++t) {
        s = fmaf(s, a_scan, sBu[t * 33 + l]);
        sSt[t * SD + l] = f2bf(s);
      }
      carry[((b * NG + g) * NC + c0 + ch) * SD + l] = s;   // [b][g][c][n]
    }
    __syncthreads();

    // states -> global (bf16), coalesced
    unsigned short* stg = (unsigned short*)(ws + WS_STL) +
                          ((size_t)((b * NC + c0 + ch) * NG + g)) * CL * SD;
    #pragma unroll
    for (int p = 0; p < 4; ++p) {
      int off = (p * 64 + l) * 8;        // 2048 ushorts
      *(short8*)(stg + off) = *(short8*)(sSt + off);
    }
    __syncthreads();   // store reads of sSt done before next chunk's scan rewrites it
  }

  // 8 special blocks emit powA and powAL tables for KB
  if (b == 0 && pc == 0 && l < SD) {
    float* powA = (float*)(ws + WS_POWA);
    float* powAL = (float*)(ws + WS_PAL);
    float p = 1.f;
    #pragma unroll
    for (int t = 0; t < CL; ++t) {
      p *= a_scan;
      powA[(g * CL + t) * SD + l] = p;
    }
    float aL = p;                       // a^64
    float q = 1.f;
    #pragma unroll
    for (int j = 0; j < CL; ++j) {
      powAL[(g * CL + j) * SD + l] = q; // aL^j
      q *= aL;
    }
  }
}

// ---------------- KB: 2-wave d-split + C GEMM + transposed coalesced y store (R19 exact) ----------------
__global__ __launch_bounds__(128) void kb_y(const float* __restrict__ u,
                                            const float* __restrict__ state0,
                                            const float* __restrict__ C,
                                            const float* __restrict__ Dp,
                                            unsigned char* __restrict__ ws,
                                            float* __restrict__ y,
                                            float* __restrict__ sfin) {
  const int bx = blockIdx.x;
  const int g = bx & (NG - 1);               // g-fastest dispatch (R19 win)
  const int c = (bx >> 3) & (NC - 1);
  const int b = bx >> 9;
  const int tid = threadIdx.x;
  const int w = tid >> 6;          // wave 0..1 -> d-half
  const int l = tid & 63;
  const int lr = l & 15, lh = l >> 4;
  const int n = l & 31;

  const float* powA = (const float*)(ws + WS_POWA) + g * CL * SD;
  const float* powAL = (const float*)(ws + WS_PAL) + g * CL * SD;
  const float* carry = (const float*)(ws + WS_CARRY) + (size_t)(b * NG + g) * NC * SD;  // [c][n]
  const unsigned short* stg = (const unsigned short*)(ws + WS_STL) + ((size_t)((b * NC + c) * NG + g)) * CL * SD;

  __shared__ __align__(16) float sY[32 * 132];   // 16896B transpose buffer

  bool need_u;
  {
    float2 dpc = *(const float2*)(Dp + g * GD + l * 2);
    need_u = __ballot((dpc.x != 0.f) || (dpc.y != 0.f)) != 0ULL;
  }

  // --- chunk-entry prefix (per wave, redundant) ---
  float p;
  {
    float a0 = 0.f, a1 = 0.f, a2 = 0.f, a3 = 0.f;
    int cc = 0;
    while (cc + 8 <= c) {
      float ca[8], wt[8];
      #pragma unroll
      for (int e = 0; e < 8; ++e) {
        ca[e] = carry[(cc + e) * SD + n];
        wt[e] = powAL[(c - 1 - cc - e) * SD + n];
      }
      a0 = fmaf(wt[0], ca[0], a0); a1 = fmaf(wt[1], ca[1], a1);
      a2 = fmaf(wt[2], ca[2], a2); a3 = fmaf(wt[3], ca[3], a3);
      a0 = fmaf(wt[4], ca[4], a0); a1 = fmaf(wt[5], ca[5], a1);
      a2 = fmaf(wt[6], ca[6], a2); a3 = fmaf(wt[7], ca[7], a3);
      cc += 8;
    }
    for (; cc < c; ++cc)
      a0 = fmaf(powAL[(c - 1 - cc) * SD + n], carry[cc * SD + n], a0);
    p = fmaf(state0[(b * NG + g) * SD + n], powAL[c * SD + n], (a0 + a1) + (a2 + a3));
  }
  if (w == 0 && c == NC - 1 && l < SD) {
    const float aL = powA[(CL - 1) * SD + l];
    sfin[(b * NG + g) * SD + l] = fmaf(p, aL, carry[(NC - 1) * SD + l]);
  }

  float pr[8];
  #pragma unroll
  for (int e = 0; e < 8; ++e) pr[e] = __shfl(p, lh * 8 + e);

  // --- corrected state fragments (B operand, col = t, k = n) ---
  short8 sf[4];
  #pragma unroll
  for (int tt = 0; tt < 4; ++tt) {
    int t = tt * 16 + lr;
    short8 sl = *(const short8*)(stg + t * SD + lh * 8);
    const float* pw = powA + t * SD + lh * 8;
    float4 pw0 = *(const float4*)pw;
    float4 pw1 = *(const float4*)(pw + 4);
    short8 hh;
    hh[0] = (short)f2bf(bf2f((unsigned short)sl[0]) + pw0.x * pr[0]);
    hh[1] = (short)f2bf(bf2f((unsigned short)sl[1]) + pw0.y * pr[1]);
    hh[2] = (short)f2bf(bf2f((unsigned short)sl[2]) + pw0.z * pr[2]);
    hh[3] = (short)f2bf(bf2f((unsigned short)sl[3]) + pw0.w * pr[3]);
    hh[4] = (short)f2bf(bf2f((unsigned short)sl[4]) + pw1.x * pr[4]);
    hh[5] = (short)f2bf(bf2f((unsigned short)sl[5]) + pw1.y * pr[5]);
    hh[6] = (short)f2bf(bf2f((unsigned short)sl[6]) + pw1.z * pr[6]);
    hh[7] = (short)f2bf(bf2f((unsigned short)sl[7]) + pw1.w * pr[7]);
    sf[tt] = hh;
  }

  // --- GEMM (swapped): D[d][t] = sum_n C[d][n]*s[t][n]; wave w owns d-half w ---
  const float* cp = C + (size_t)g * GD * SD;
  const size_t rowbase = ((size_t)b * TT + (size_t)c * CL) * DM + g * GD;

  short8 cf[4];
  #pragma unroll
  for (int dd = 0; dd < 4; ++dd) {
    int d = (w * 4 + dd) * 16 + lr;
    const float* pp = cp + (size_t)d * SD + lh * 8;
    float4 v0 = *(const float4*)pp;
    float4 v1 = *(const float4*)(pp + 4);
    cf[dd] = pack8(v0, v1);
  }
  f32x4 acc[4][4];
  #pragma unroll
  for (int dd = 0; dd < 4; ++dd)
    #pragma unroll
    for (int tt = 0; tt < 4; ++tt) {
      f32x4 z;
      #pragma unroll
      for (int j = 0; j < 4; ++j) z[j] = 0.f;
      acc[dd][tt] = __builtin_amdgcn_mfma_f32_16x16x32_bf16(cf[dd], sf[tt], z, 0, 0, 0);
    }

  // --- epilogue: LDS transpose (two 32-t halves) -> fully coalesced y stores ---
  const int sd4 = (tid & 31) * 4;
  float4 dpv = *(const float4*)(Dp + g * GD + sd4);

  #pragma unroll
  for (int tp = 0; tp < 2; ++tp) {
    if (tp) __syncthreads();
    #pragma unroll
    for (int dd = 0; dd < 4; ++dd)
      #pragma unroll
      for (int q = 0; q < 2; ++q) {
        int tt = tp * 2 + q;
        int tl = q * 16 + lr;
        int d0 = (w * 4 + dd) * 16 + lh * 4;
        *(float4*)(sY + tl * 132 + d0) = (float4){acc[dd][tt][0], acc[dd][tt][1],
                                                  acc[dd][tt][2], acc[dd][tt][3]};
      }
    __syncthreads();
    #pragma unroll
    for (int r = 0; r < 8; ++r) {
      int tl = r * 4 + (tid >> 5);
      int t = tp * 32 + tl;
      float4 v = *(const float4*)(sY + tl * 132 + sd4);
      size_t off = rowbase + (size_t)t * DM + sd4;
      if (need_u) {
        float4 u4 = *(const float4*)(u + off);
        v.x += dpv.x * u4.x; v.y += dpv.y * u4.y;
        v.z += dpv.z * u4.z; v.w += dpv.w * u4.w;
      }
      *(float4*)(y + off) = v;
    }
  }
}

extern "C" void kernel_launch(void* const* d_in, const int* in_sizes, int n_in,
                              void* d_out, int out_size, void* d_ws, size_t ws_size,
                              hipStream_t stream) {
  const float* u       = (const float*)d_in[0];
  const float* state0  = (const float*)d_in[1];
  const float* A_log   = (const float*)d_in[2];
  const float* B_param = (const float*)d_in[3];
  const float* C       = (const float*)d_in[4];
  const float* Dp      = (const float*)d_in[5];
  const float* dtl     = (const float*)d_in[6];
  float* y = (float*)d_out;
  unsigned char* ws = (unsigned char*)d_ws;
  float* sfin = y + (size_t)BS * TT * DM;

  ka_bu_scan<<<dim3(BS * NG * NC / 2), dim3(64), 0, stream>>>(u, A_log, B_param, dtl, ws);
  kb_y<<<dim3(BS * NG * NC), dim3(128), 0, stream>>>(u, state0, C, Dp, ws, y, sfin);
}